// Round 13
// baseline (297.821 us; speedup 1.0000x reference)
//
#include <hip/hip_runtime.h>
#include <hip/hip_bf16.h>
#include <hip/hip_fp16.h>

#define TPB 256

typedef _Float16 half8 __attribute__((ext_vector_type(8)));
typedef float f32x4 __attribute__((ext_vector_type(4)));
typedef unsigned long long ull;

#define SCAN_T 1024
#define SCAN_PER 4
#define NSCAN 13          // ceil(50000 / 4096)

// ---------------- prep: edge count (+pos), W2 -> fp16, zero d_out ----------------

__global__ void fused_prep(const int* __restrict__ ei, int* __restrict__ cnt,
                           int* __restrict__ pos,
                           const float* __restrict__ Wc2, const float* __restrict__ Wv2,
                           __half* __restrict__ Wch, __half* __restrict__ Wvh2,
                           float* __restrict__ out0, int Nout, int E, int nbE) {
    int bid = blockIdx.x;
    int t = threadIdx.x;
    if (bid < nbE) {
        int e = bid * TPB + t;
        if (e < E) {
            int d = ei[E + e];
            pos[e] = atomicAdd(&cnt[d], 1);
        }
    } else {
        int i = (bid - nbE) * TPB + t;
        if (i < 128 * 128) {
            Wch[i]  = __float2half_rn(Wc2[i]);
            Wvh2[i] = __float2half_rn(Wv2[i]);
        }
        for (int j = i; j < Nout; j += 64 * TPB) out0[j] = 0.f;
    }
}

// ---------------- scan: 13 lookback blocks ONLY (peer chain = safe pattern) ------

__global__ __launch_bounds__(SCAN_T)
void scan_lookback(const int* __restrict__ cnt, int* __restrict__ rowptr,
                   float* __restrict__ dis, int* __restrict__ flags,
                   int N, int E) {
    __shared__ int sd[SCAN_T];
    __shared__ int s_prev;
    int t = threadIdx.x, b = blockIdx.x;
    int base = b * (SCAN_T * SCAN_PER) + t * SCAN_PER;
    int v[SCAN_PER];
    int s = 0;
#pragma unroll
    for (int k = 0; k < SCAN_PER; ++k) {
        int i = base + k;
        v[k] = (i < N) ? cnt[i] : 0;
        s += v[k];
    }
    sd[t] = s;
    __syncthreads();
    for (int off = 1; off < SCAN_T; off <<= 1) {
        int x = 0;
        if (t >= off) x = sd[t - off];
        __syncthreads();
        sd[t] += x;
        __syncthreads();
    }
    int excl = sd[t] - s;
    if (t == 0) {
        int prev = 0;
        if (b > 0) {
            int f;
            while ((f = __hip_atomic_load(flags + b - 1, __ATOMIC_ACQUIRE,
                                          __HIP_MEMORY_SCOPE_AGENT)) == 0) {}
            prev = f - 1;
        }
        __hip_atomic_store(flags + b, prev + sd[SCAN_T - 1] + 1,
                           __ATOMIC_RELEASE, __HIP_MEMORY_SCOPE_AGENT);
        s_prev = prev;
    }
    __syncthreads();
    int run = s_prev + excl;
#pragma unroll
    for (int k = 0; k < SCAN_PER; ++k) {
        int i = base + k;
        if (i < N) {
            rowptr[i] = run;
            dis[i] = rsqrtf((float)(v[k] + 1));
            run += v[k];
        }
    }
    if (b == 0 && t == 0) rowptr[N] = E;
}

// ---------------- CSR fill (atomic-free): rec[e] = {dis[src] : src} --------------

__global__ void fill_csr(const int* __restrict__ ei, const int* __restrict__ rowptr,
                         const int* __restrict__ pos, const float* __restrict__ dis,
                         ull* __restrict__ rec, int E) {
    int e = blockIdx.x * TPB + threadIdx.x;
    if (e >= E) return;
    int s = ei[e], d = ei[E + e];
    int p = rowptr[d] + pos[e];
    rec[p] = ((ull)__float_as_uint(dis[s]) << 32) | (unsigned)s;
}

// ---------------- fused layer 1 + layer-2 transform + feature-major repack -------
// Per block of 64 nodes:
//  1) xagg[i] = dis_i*(sum_s dis_s x_s + dis_i x_i)   (16-dim fp32, L2-resident)
//  2) h1 = relu(xagg @ W1^T + b1) -> LDS fp16
//  3) A-frags preloaded to registers, then t2 = h1 @ W2^T via MFMA -> LDS t2s
//     (aliased over h1s), then repack to feature-major global:
//     tout[slice][node][32 fp16], slice = feat>>5.

__global__ __launch_bounds__(256)
void fused_l1(const float* __restrict__ x, const int* __restrict__ rowptr,
              const ull* __restrict__ rec, const float* __restrict__ dis,
              const float* __restrict__ Wc1, const float* __restrict__ bc1,
              const float* __restrict__ Wv1, const float* __restrict__ bv1,
              const __half* __restrict__ Wch, const __half* __restrict__ Wvh2,
              __half* __restrict__ tout, int N, int Npad) {
    __shared__ float xt[64][16];
    __shared__ _Float16 h1s[64][272];     // aliased as t2s[8][64][34] in phase 3
    int tid = threadIdx.x;
    int wave = tid >> 6, lane = tid & 63;

    // ---- phase 1: gather (wave = 16 nodes, lane-group of 4 = one node) ----------
    {
        int g = lane >> 2, q = lane & 3;
        int n = wave * 16 + g;
        int node = blockIdx.x * 64 + n;
        if (node < N) {
            float dn = dis[node];
            float4 xs = *(const float4*)(x + (size_t)node * 16 + q * 4);
            float ax = dn * xs.x, ay = dn * xs.y, az = dn * xs.z, aw = dn * xs.w;
            int e = rowptr[node], end = rowptr[node + 1];
            const ull sent = (ull)(unsigned)node;      // ds=+0 -> no contribution
            ull r0 = (e < end) ? rec[e] : sent;
            ull r1 = (e + 1 < end) ? rec[e + 1] : sent;
            for (; e < end; e += 2) {
                int s0 = (int)(unsigned)r0, s1 = (int)(unsigned)r1;
                float d0 = __uint_as_float((unsigned)(r0 >> 32));
                float d1 = __uint_as_float((unsigned)(r1 >> 32));
                float4 x0 = *(const float4*)(x + (size_t)s0 * 16 + q * 4);
                float4 x1 = *(const float4*)(x + (size_t)s1 * 16 + q * 4);
                int en = e + 2;
                r0 = (en < end) ? rec[en] : sent;
                r1 = (en + 1 < end) ? rec[en + 1] : sent;
                ax = fmaf(d0, x0.x, fmaf(d1, x1.x, ax));
                ay = fmaf(d0, x0.y, fmaf(d1, x1.y, ay));
                az = fmaf(d0, x0.z, fmaf(d1, x1.z, az));
                aw = fmaf(d0, x0.w, fmaf(d1, x1.w, aw));
            }
            float4 o = make_float4(dn * ax, dn * ay, dn * az, dn * aw);
            *(float4*)(&xt[n][q * 4]) = o;
        } else {
            *(float4*)(&xt[n][q * 4]) = make_float4(0.f, 0.f, 0.f, 0.f);
        }
    }
    __syncthreads();

    // ---- phase 2: h1 = relu(xagg @ W1^T + b); thread = cols 4l..4l+3, 16 rows ---
    {
        int c0 = lane * 4;
        float4 wr[4][4];
        float bias[4];
#pragma unroll
        for (int j = 0; j < 4; ++j) {
            int c = c0 + j;
            const float* row = (c < 128) ? (Wc1 + c * 16) : (Wv1 + (c - 128) * 16);
            wr[j][0] = *(const float4*)(row + 0);
            wr[j][1] = *(const float4*)(row + 4);
            wr[j][2] = *(const float4*)(row + 8);
            wr[j][3] = *(const float4*)(row + 12);
            bias[j] = (c < 128) ? bc1[c] : bv1[c - 128];
        }
        int r0 = wave * 16;
        for (int nn = r0; nn < r0 + 16; ++nn) {
            float4 xa = *(const float4*)(&xt[nn][0]);
            float4 xb = *(const float4*)(&xt[nn][4]);
            float4 xc = *(const float4*)(&xt[nn][8]);
            float4 xd = *(const float4*)(&xt[nn][12]);
            float sv[4];
#pragma unroll
            for (int j = 0; j < 4; ++j) {
                float s = wr[j][0].x * xa.x + wr[j][0].y * xa.y
                        + wr[j][0].z * xa.z + wr[j][0].w * xa.w
                        + wr[j][1].x * xb.x + wr[j][1].y * xb.y
                        + wr[j][1].z * xb.z + wr[j][1].w * xb.w
                        + wr[j][2].x * xc.x + wr[j][2].y * xc.y
                        + wr[j][2].z * xc.z + wr[j][2].w * xc.w
                        + wr[j][3].x * xd.x + wr[j][3].y * xd.y
                        + wr[j][3].z * xd.z + wr[j][3].w * xd.w;
                sv[j] = fmaxf(s + bias[j], 0.f);
            }
            __half2 o01 = __floats2half2_rn(sv[0], sv[1]);
            __half2 o23 = __floats2half2_rn(sv[2], sv[3]);
            uint2 pk;
            pk.x = *reinterpret_cast<unsigned*>(&o01);
            pk.y = *reinterpret_cast<unsigned*>(&o23);
            *(uint2*)(&h1s[nn][c0]) = pk;
        }
    }
    __syncthreads();

    // ---- phase 3a: preload A fragments (both branches) from h1s -----------------
    int quad = lane >> 4, l16 = lane & 15;
    half8 A0[4], A1[4];
    {
        const _Float16* ar0 = &h1s[wave * 16 + l16][quad * 8];
        A0[0] = *(const half8*)(ar0 + 0);
        A0[1] = *(const half8*)(ar0 + 32);
        A0[2] = *(const half8*)(ar0 + 64);
        A0[3] = *(const half8*)(ar0 + 96);
        const _Float16* ar1 = ar0 + 128;
        A1[0] = *(const half8*)(ar1 + 0);
        A1[1] = *(const half8*)(ar1 + 32);
        A1[2] = *(const half8*)(ar1 + 64);
        A1[3] = *(const half8*)(ar1 + 96);
    }
    __syncthreads();                       // all A-frags read; h1s reusable

    // ---- phase 3b: MFMA t2 = h1 @ W^T -> LDS t2s (aliased) ----------------------
    _Float16 (*t2s)[64][34] = (_Float16 (*)[64][34])&h1s[0][0];
#pragma unroll
    for (int br = 0; br < 2; ++br) {
        const _Float16* W = br ? (const _Float16*)Wvh2 : (const _Float16*)Wch;
        int koff = br * 128;
#pragma unroll
        for (int jj = 0; jj < 8; ++jj) {
            const _Float16* wr = W + (size_t)(jj * 16 + l16) * 128 + quad * 8;
            half8 b0 = *(const half8*)(wr + 0);
            half8 b1 = *(const half8*)(wr + 32);
            half8 b2 = *(const half8*)(wr + 64);
            half8 b3 = *(const half8*)(wr + 96);
            f32x4 acc = {0.f, 0.f, 0.f, 0.f};
            if (br == 0) {
                acc = __builtin_amdgcn_mfma_f32_16x16x32_f16(A0[0], b0, acc, 0, 0, 0);
                acc = __builtin_amdgcn_mfma_f32_16x16x32_f16(A0[1], b1, acc, 0, 0, 0);
                acc = __builtin_amdgcn_mfma_f32_16x16x32_f16(A0[2], b2, acc, 0, 0, 0);
                acc = __builtin_amdgcn_mfma_f32_16x16x32_f16(A0[3], b3, acc, 0, 0, 0);
            } else {
                acc = __builtin_amdgcn_mfma_f32_16x16x32_f16(A1[0], b0, acc, 0, 0, 0);
                acc = __builtin_amdgcn_mfma_f32_16x16x32_f16(A1[1], b1, acc, 0, 0, 0);
                acc = __builtin_amdgcn_mfma_f32_16x16x32_f16(A1[2], b2, acc, 0, 0, 0);
                acc = __builtin_amdgcn_mfma_f32_16x16x32_f16(A1[3], b3, acc, 0, 0, 0);
            }
            int fo = koff + jj * 16 + l16;
            int s = fo >> 5, idx = fo & 31;
#pragma unroll
            for (int r = 0; r < 4; ++r)
                t2s[s][wave * 16 + quad * 4 + r][idx] = (_Float16)acc[r];
        }
    }
    __syncthreads();

    // ---- phase 3c: repack LDS -> feature-major global (64 B chunks) -------------
    for (int i = tid; i < 512; i += 256) {
        int s = i >> 6, n = i & 63;
        int node = blockIdx.x * 64 + n;
        if (node >= N) continue;
        const unsigned* sw = (const unsigned*)&t2s[s][n][0];   // 4 B aligned
        unsigned d[16];
#pragma unroll
        for (int k = 0; k < 16; ++k) d[k] = sw[k];
        uint4* dst = (uint4*)tout + ((size_t)s * Npad + node) * 4;
        dst[0] = make_uint4(d[0], d[1], d[2], d[3]);
        dst[1] = make_uint4(d[4], d[5], d[6], d[7]);
        dst[2] = make_uint4(d[8], d[9], d[10], d[11]);
        dst[3] = make_uint4(d[12], d[13], d[14], d[15]);
    }
}

// ---------------- agg2 + heads, slice-partitioned (feature-major table) ----------
// slice = blockIdx%8 -> XCD-pinned; per-XCD gather working set = 3.2 MB (L2-fits).
// Half-wave = one (node, slice): 8 edge-groups x 4 lanes (16 B each), 8 edges
// in flight. Head partials -> atomicAdd into zeroed d_out.

__global__ __launch_bounds__(256)
void agg2(const uint4* __restrict__ tin, const int* __restrict__ rowptr,
          const ull* __restrict__ rec, const float* __restrict__ dis,
          const float* __restrict__ bc, const float* __restrict__ bv,
          const float* __restrict__ Wp, const float* __restrict__ bp,
          const float* __restrict__ Wvh, const float* __restrict__ bvh,
          float* __restrict__ outm, float* __restrict__ outv, int N, int Npad) {
    int slice = blockIdx.x & 7;
    int lane = threadIdx.x & 63;
    int half = lane >> 5, sl = lane & 31;
    int node = (blockIdx.x >> 3) * 8 + ((threadIdx.x >> 6) << 1) + half;
    if (node >= N) return;
    int g = sl >> 2, q = sl & 3;
    size_t sbase = (size_t)slice * Npad;
    float dn = dis[node];

    float a[8];
    {   // self term (group 0 only; others init 0)
        uint4 ms = tin[(sbase + node) * 4 + q];
        float2 f0 = __half22float2(*reinterpret_cast<const __half2*>(&ms.x));
        float2 f1 = __half22float2(*reinterpret_cast<const __half2*>(&ms.y));
        float2 f2 = __half22float2(*reinterpret_cast<const __half2*>(&ms.z));
        float2 f3 = __half22float2(*reinterpret_cast<const __half2*>(&ms.w));
        float w = (g == 0) ? dn : 0.f;
        a[0] = w * f0.x; a[1] = w * f0.y; a[2] = w * f1.x; a[3] = w * f1.y;
        a[4] = w * f2.x; a[5] = w * f2.y; a[6] = w * f3.x; a[7] = w * f3.y;
    }
    int e0 = rowptr[node], end = rowptr[node + 1];
    const ull sent = (ull)(unsigned)node;              // ds=+0
    int e = e0 + g;
    ull r = (e < end) ? rec[e] : sent;
    for (int eb = e0; eb < end; eb += 8) {
        int src = (int)(unsigned)r;
        float ds = __uint_as_float((unsigned)(r >> 32));
        int en = e + 8;
        ull rn = (en < end) ? rec[en] : sent;
        uint4 m = tin[(sbase + src) * 4 + q];
        float2 f0 = __half22float2(*reinterpret_cast<const __half2*>(&m.x));
        float2 f1 = __half22float2(*reinterpret_cast<const __half2*>(&m.y));
        float2 f2 = __half22float2(*reinterpret_cast<const __half2*>(&m.z));
        float2 f3 = __half22float2(*reinterpret_cast<const __half2*>(&m.w));
        a[0] = fmaf(ds, f0.x, a[0]); a[1] = fmaf(ds, f0.y, a[1]);
        a[2] = fmaf(ds, f1.x, a[2]); a[3] = fmaf(ds, f1.y, a[3]);
        a[4] = fmaf(ds, f2.x, a[4]); a[5] = fmaf(ds, f2.y, a[5]);
        a[6] = fmaf(ds, f3.x, a[6]); a[7] = fmaf(ds, f3.y, a[7]);
        r = rn; e = en;
    }
    // reduce over the 8 edge-groups (stride 4, q preserved)
#pragma unroll
    for (int off = 16; off >= 4; off >>= 1) {
#pragma unroll
        for (int k = 0; k < 8; ++k) a[k] += __shfl_down(a[k], off, 32);
    }
    // epilogue: lanes sl<4 hold the 32 aggregated feats of this slice
    float p = 0.f;
    if (sl < 4) {
        int F = slice * 32 + sl * 8;
        bool pol = (slice < 4);
        const float* bb = pol ? (bc + F) : (bv + F - 128);
        const float* wwp = pol ? (Wp + F) : (Wvh + F - 128);
        float4 bA = *(const float4*)bb;
        float4 bB = *(const float4*)(bb + 4);
        float4 wA = *(const float4*)wwp;
        float4 wB = *(const float4*)(wwp + 4);
        p = fmaxf(fmaf(dn, a[0], bA.x), 0.f) * wA.x
          + fmaxf(fmaf(dn, a[1], bA.y), 0.f) * wA.y
          + fmaxf(fmaf(dn, a[2], bA.z), 0.f) * wA.z
          + fmaxf(fmaf(dn, a[3], bA.w), 0.f) * wA.w
          + fmaxf(fmaf(dn, a[4], bB.x), 0.f) * wB.x
          + fmaxf(fmaf(dn, a[5], bB.y), 0.f) * wB.y
          + fmaxf(fmaf(dn, a[6], bB.z), 0.f) * wB.z
          + fmaxf(fmaf(dn, a[7], bB.w), 0.f) * wB.w;
    }
    p += __shfl_down(p, 2, 32);
    p += __shfl_down(p, 1, 32);
    if (sl == 0) {
        if (slice == 0) p += bp[0];
        if (slice == 4) p += bvh[0];
        atomicAdd((slice < 4) ? (outm + node) : (outv + node), p);
    }
}

// ---------------- launch ---------------------------------------------------------

extern "C" void kernel_launch(void* const* d_in, const int* in_sizes, int n_in,
                              void* d_out, int out_size, void* d_ws, size_t ws_size,
                              hipStream_t stream) {
    const float* x   = (const float*)d_in[0];
    const int*   ei  = (const int*)  d_in[1];
    const float* Wc1 = (const float*)d_in[2];
    const float* bc1 = (const float*)d_in[3];
    const float* Wc2 = (const float*)d_in[4];
    const float* bc2 = (const float*)d_in[5];
    const float* Wp  = (const float*)d_in[6];
    const float* bp  = (const float*)d_in[7];
    const float* Wv1 = (const float*)d_in[8];
    const float* bv1 = (const float*)d_in[9];
    const float* Wv2 = (const float*)d_in[10];
    const float* bv2 = (const float*)d_in[11];
    const float* Wvh = (const float*)d_in[12];
    const float* bvh = (const float*)d_in[13];

    const int N = in_sizes[0] / 16;   // 50000
    const int E = in_sizes[1] / 2;    // 800000
    const int Npad = (N + 63) & ~63;

    size_t off = 0;
    auto alloc = [&](size_t bytes) -> void* {
        void* p = (char*)d_ws + off;
        off += (bytes + 255) & ~(size_t)255;
        return p;
    };
    int*    cnt    = (int*)alloc((size_t)(N + 64) * sizeof(int));
    int*    flags  = cnt + N;        // 16 slots, zeroed by the same memset
    int*    pos    = (int*)alloc((size_t)E * sizeof(int));
    int*    rowptr = (int*)alloc((size_t)(N + 1) * sizeof(int));
    float*  dis    = (float*)alloc((size_t)Npad * sizeof(float));
    ull*    rec    = (ull*)alloc((size_t)E * sizeof(ull));                // 6.4 MB
    __half* Wch    = (__half*)alloc(128 * 128 * sizeof(__half));
    __half* Wvh2   = (__half*)alloc(128 * 128 * sizeof(__half));
    __half* tbuf   = (__half*)alloc((size_t)Npad * 256 * sizeof(__half)); // 25.6 MB

    float* outm = (float*)d_out;
    float* outv = outm + N;

    const int nbE = (E + TPB - 1) / TPB;              // 3125

    (void)hipMemsetAsync(cnt, 0, (size_t)(N + 64) * sizeof(int), stream);

    fused_prep<<<nbE + 64, TPB, 0, stream>>>(ei, cnt, pos, Wc2, Wv2, Wch, Wvh2,
                                             (float*)d_out, 2 * N, E, nbE);
    scan_lookback<<<NSCAN, SCAN_T, 0, stream>>>(cnt, rowptr, dis, flags, N, E);
    fill_csr<<<nbE, TPB, 0, stream>>>(ei, rowptr, pos, dis, rec, E);
    fused_l1<<<(N + 63) / 64, 256, 0, stream>>>(x, rowptr, rec, dis,
                                                Wc1, bc1, Wv1, bv1,
                                                Wch, Wvh2, tbuf, N, Npad);
    agg2<<<((N + 7) / 8) * 8, 256, 0, stream>>>((const uint4*)tbuf, rowptr, rec,
                                                dis, bc2, bv2, Wp, bp, Wvh, bvh,
                                                outm, outv, N, Npad);
}